// Round 1
// baseline (3390.095 us; speedup 1.0000x reference)
//
#include <hip/hip_runtime.h>
#include <math.h>

// SimpleRetention: out = (softmax(Q Kt) * gamma^|n-m|) @ V,  Q/K xpos-rotated X@W
// B=8 L=2048 H=Dh=1024.  Round 1: correct fp32 baseline.
// Workspace: Q,K,V fp32 = 3 * 16384*1024*4 = 192MB (assumed <= ws_size).

#define BDIM 8
#define LDIM 2048
#define HDIM 1024
#define MTOT (BDIM * LDIM)   // 16384

// ---------------------------------------------------------------------------
// K1: C = X @ W  (M=16384, K=1024, N=1024) for W in {Wq,Wk,Wv}; fused xpos.
// 128x128 tile, BK=16, 256 threads, 8x8 micro (split 4+4 over the 64/128 halves).
// ---------------------------------------------------------------------------
__global__ __launch_bounds__(256)
void qkv_xpos_gemm(const float* __restrict__ X, const float* __restrict__ Wq,
                   const float* __restrict__ Wk, const float* __restrict__ Wv,
                   float* __restrict__ Qo, float* __restrict__ Ko, float* __restrict__ Vo)
{
    const int z = blockIdx.z;
    const float* __restrict__ W = (z == 0) ? Wq : (z == 1) ? Wk : Wv;
    float* __restrict__ Out = (z == 0) ? Qo : (z == 1) ? Ko : Vo;

    const int m0 = blockIdx.y * 128;
    const int n0 = blockIdx.x * 128;
    const int tid = threadIdx.x;
    const int tx = tid & 15;
    const int ty = tid >> 4;

    __shared__ float As[16][132];   // [k][m] (transposed A tile), pad stride 132
    __shared__ float Bs[16][132];   // [k][n]

    float c[8][8];
#pragma unroll
    for (int i = 0; i < 8; ++i)
#pragma unroll
        for (int j = 0; j < 8; ++j) c[i][j] = 0.0f;

    const int ar  = tid >> 2;          // 0..63
    const int ac4 = (tid & 3) * 4;     // 0,4,8,12
    const int br  = tid >> 4;          // 0..15
    const int bc8 = (tid & 15) * 8;    // 0..120

    for (int k0 = 0; k0 < HDIM; k0 += 16) {
        __syncthreads();
        // stage A: X[m0..m0+127][k0..k0+15] -> As[k][m]
        float4 va0 = *(const float4*)&X[(size_t)(m0 + ar) * HDIM + k0 + ac4];
        float4 va1 = *(const float4*)&X[(size_t)(m0 + 64 + ar) * HDIM + k0 + ac4];
        As[ac4 + 0][ar] = va0.x; As[ac4 + 1][ar] = va0.y;
        As[ac4 + 2][ar] = va0.z; As[ac4 + 3][ar] = va0.w;
        As[ac4 + 0][64 + ar] = va1.x; As[ac4 + 1][64 + ar] = va1.y;
        As[ac4 + 2][64 + ar] = va1.z; As[ac4 + 3][64 + ar] = va1.w;
        // stage B: W[k0..k0+15][n0..n0+127] -> Bs[k][n]
        float4 vb0 = *(const float4*)&W[(size_t)(k0 + br) * HDIM + n0 + bc8];
        float4 vb1 = *(const float4*)&W[(size_t)(k0 + br) * HDIM + n0 + bc8 + 4];
        *(float4*)&Bs[br][bc8]     = vb0;
        *(float4*)&Bs[br][bc8 + 4] = vb1;
        __syncthreads();
#pragma unroll
        for (int dk = 0; dk < 16; ++dk) {
            float4 a0 = *(const float4*)&As[dk][ty * 4];
            float4 a1 = *(const float4*)&As[dk][64 + ty * 4];
            float4 b0 = *(const float4*)&Bs[dk][tx * 4];
            float4 b1 = *(const float4*)&Bs[dk][64 + tx * 4];
            float a[8] = {a0.x, a0.y, a0.z, a0.w, a1.x, a1.y, a1.z, a1.w};
            float b[8] = {b0.x, b0.y, b0.z, b0.w, b1.x, b1.y, b1.z, b1.w};
#pragma unroll
            for (int i = 0; i < 8; ++i)
#pragma unroll
                for (int j = 0; j < 8; ++j)
                    c[i][j] = fmaf(a[i], b[j], c[i][j]);
        }
    }

    // epilogue: xpos for z<2 (Q: *scale, K: /scale), then store
#pragma unroll
    for (int i = 0; i < 8; ++i) {
        const int gm = m0 + ((i < 4) ? (ty * 4 + i) : (64 + ty * 4 + (i - 4)));
        const int l  = gm & (LDIM - 1);     // position within sequence
        if (z < 2) {
            const float pw = (float)l * (1.0f / 512.0f) * ((z == 0) ? 1.0f : -1.0f);
#pragma unroll
            for (int jp = 0; jp < 4; ++jp) {
                const int j0 = jp * 2;
                const int gc = n0 + ((j0 < 4) ? (tx * 4 + j0) : (64 + tx * 4 + (j0 - 4)));
                const int ih = gc >> 1;     // half-dim index
                // inv_freq = 10000^(-ih/512) = 2^(-ih/512 * log2(10000))
                float invf = exp2f(-13.287712379549449f * (1.0f / 512.0f) * (float)ih);
                float ang  = (float)l * invf;
                float sn, cs;
                sincosf(ang, &sn, &cs);
                // scale_vec = (2*ih + 0.4*1024)/(1.4*1024); scale = sv^(l/512) (K: ^-1)
                float sv  = ((float)(2 * ih) + 409.6f) * (1.0f / 1433.6f);
                float scl = exp2f(pw * log2f(sv));
                float e = c[i][j0], o = c[i][j0 + 1];
                c[i][j0]     = (e * cs - o * sn) * scl;
                c[i][j0 + 1] = (o * cs + e * sn) * scl;
            }
        }
        float4 o0 = {c[i][0], c[i][1], c[i][2], c[i][3]};
        float4 o1 = {c[i][4], c[i][5], c[i][6], c[i][7]};
        *(float4*)&Out[(size_t)gm * HDIM + n0 + tx * 4]      = o0;
        *(float4*)&Out[(size_t)gm * HDIM + n0 + 64 + tx * 4] = o1;
    }
}

// ---------------------------------------------------------------------------
// K2: retention attention, no-max-needed softmax (scores bounded ~|7| << 88).
// out[q,:] = (sum_k exp(s)*gamma^|q-k| * V[k,:]) / (sum_k exp(s))
// Block: one (batch, 16-query tile); 256 threads; K-strips of 256.
// batch = blockIdx.x & 7  -> each XCD's blocks share one batch's K/V in L2.
// ---------------------------------------------------------------------------
#define TQ 16
#define TK 256
#define DKC 32

__global__ __launch_bounds__(256)
void retention_attn(const float* __restrict__ Q, const float* __restrict__ K,
                    const float* __restrict__ V, float* __restrict__ Out)
{
    const int bid   = blockIdx.x;
    const int batch = bid & 7;
    const int qb    = bid >> 3;
    const int q0    = qb * TQ;
    const int tid   = threadIdx.x;
    const int qg    = tid >> 6;   // 0..3  (wave-uniform)
    const int kg    = tid & 63;   // 0..63

    __shared__ float Qst[DKC][20];    // [dk][q]
    __shared__ float Kst[DKC][260];   // [dk][k]
    __shared__ float Wl[TQ][TK];      // weights exp(s)*gamma^|d|
    __shared__ float Zred[TQ][65];
    __shared__ float Zfin[TQ];

    float4 acc[TQ];
#pragma unroll
    for (int q = 0; q < TQ; ++q) acc[q] = make_float4(0.f, 0.f, 0.f, 0.f);
    float zpart[4] = {0.f, 0.f, 0.f, 0.f};

    const float* __restrict__ Qb = Q + (size_t)(batch * LDIM + q0) * HDIM;
    const float* __restrict__ Kb = K + (size_t)batch * LDIM * HDIM;
    const float* __restrict__ Vb = V + (size_t)batch * LDIM * HDIM;

    const float LOG2E = 1.4426950408889634f;
    const float LOG2G = -0.15200309344504997f;   // log2(0.9)

    for (int s = 0; s < LDIM / TK; ++s) {
        const int k0 = s * TK;
        float sc[4][4];
#pragma unroll
        for (int i = 0; i < 4; ++i)
#pragma unroll
            for (int j = 0; j < 4; ++j) sc[i][j] = 0.f;

        for (int ch = 0; ch < HDIM / DKC; ++ch) {
            __syncthreads();
            if (tid < 128) {   // stage Q chunk 16x32 (transposed)
                const int r = tid >> 3, c4 = (tid & 7) * 4;
                float4 v = *(const float4*)&Qb[(size_t)r * HDIM + ch * DKC + c4];
                Qst[c4 + 0][r] = v.x; Qst[c4 + 1][r] = v.y;
                Qst[c4 + 2][r] = v.z; Qst[c4 + 3][r] = v.w;
            }
            {   // stage K chunk 256x32 (transposed); one 128B line per row per chunk
                const int kr = tid >> 3, kc4 = (tid & 7) * 4;
#pragma unroll
                for (int p = 0; p < 8; ++p) {
                    const int rk = p * 32 + kr;
                    float4 v = *(const float4*)&Kb[(size_t)(k0 + rk) * HDIM + ch * DKC + kc4];
                    Kst[kc4 + 0][rk] = v.x; Kst[kc4 + 1][rk] = v.y;
                    Kst[kc4 + 2][rk] = v.z; Kst[kc4 + 3][rk] = v.w;
                }
            }
            __syncthreads();
#pragma unroll
            for (int dk = 0; dk < DKC; ++dk) {
                float4 a = *(const float4*)&Qst[dk][qg * 4];   // wave-broadcast
                float4 b = *(const float4*)&Kst[dk][kg * 4];   // contiguous 1KB
                float av[4] = {a.x, a.y, a.z, a.w};
                float bv[4] = {b.x, b.y, b.z, b.w};
#pragma unroll
                for (int i = 0; i < 4; ++i)
#pragma unroll
                    for (int j = 0; j < 4; ++j)
                        sc[i][j] = fmaf(av[i], bv[j], sc[i][j]);
            }
        }

        // exp + decay, accumulate Z partials, publish weights
#pragma unroll
        for (int i = 0; i < 4; ++i) {
            const int qglob = q0 + qg * 4 + i;
            float w[4];
#pragma unroll
            for (int j = 0; j < 4; ++j) {
                const int kglob = k0 + kg * 4 + j;
                float e = exp2f(sc[i][j] * LOG2E);
                zpart[i] += e;
                int dd = qglob - kglob; if (dd < 0) dd = -dd;
                w[j] = e * exp2f((float)dd * LOG2G);
            }
            float4 wv = {w[0], w[1], w[2], w[3]};
            *(float4*)&Wl[qg * 4 + i][kg * 4] = wv;
        }
        __syncthreads();

        // PV: thread owns d columns tid*4..tid*4+3
        for (int k4 = 0; k4 < TK / 4; ++k4) {
            const float* vb = &Vb[(size_t)(k0 + k4 * 4) * HDIM + tid * 4];
            float4 v0 = *(const float4*)(vb);
            float4 v1 = *(const float4*)(vb + HDIM);
            float4 v2 = *(const float4*)(vb + 2 * HDIM);
            float4 v3 = *(const float4*)(vb + 3 * HDIM);
#pragma unroll
            for (int q = 0; q < TQ; ++q) {
                float4 w4 = *(const float4*)&Wl[q][k4 * 4];    // broadcast b128
                acc[q].x = fmaf(w4.x, v0.x, acc[q].x);
                acc[q].x = fmaf(w4.y, v1.x, acc[q].x);
                acc[q].x = fmaf(w4.z, v2.x, acc[q].x);
                acc[q].x = fmaf(w4.w, v3.x, acc[q].x);
                acc[q].y = fmaf(w4.x, v0.y, acc[q].y);
                acc[q].y = fmaf(w4.y, v1.y, acc[q].y);
                acc[q].y = fmaf(w4.z, v2.y, acc[q].y);
                acc[q].y = fmaf(w4.w, v3.y, acc[q].y);
                acc[q].z = fmaf(w4.x, v0.z, acc[q].z);
                acc[q].z = fmaf(w4.y, v1.z, acc[q].z);
                acc[q].z = fmaf(w4.z, v2.z, acc[q].z);
                acc[q].z = fmaf(w4.w, v3.z, acc[q].z);
                acc[q].w = fmaf(w4.x, v0.w, acc[q].w);
                acc[q].w = fmaf(w4.y, v1.w, acc[q].w);
                acc[q].w = fmaf(w4.z, v2.w, acc[q].w);
                acc[q].w = fmaf(w4.w, v3.w, acc[q].w);
            }
        }
        // next strip's first chunk barrier orders Wl reuse
    }

    // reduce Z across the 64 k-groups
#pragma unroll
    for (int i = 0; i < 4; ++i) Zred[qg * 4 + i][kg] = zpart[i];
    __syncthreads();
    if (tid < TQ) {
        float zz = 0.f;
        for (int k = 0; k < 64; ++k) zz += Zred[tid][k];
        Zfin[tid] = zz;
    }
    __syncthreads();

    float* Ob = Out + (size_t)(batch * LDIM + q0) * HDIM;
#pragma unroll
    for (int q = 0; q < TQ; ++q) {
        const float inv = 1.0f / Zfin[q];
        float4 o = {acc[q].x * inv, acc[q].y * inv, acc[q].z * inv, acc[q].w * inv};
        *(float4*)&Ob[(size_t)q * HDIM + tid * 4] = o;
    }
}

// ---------------------------------------------------------------------------
extern "C" void kernel_launch(void* const* d_in, const int* in_sizes, int n_in,
                              void* d_out, int out_size, void* d_ws, size_t ws_size,
                              hipStream_t stream)
{
    (void)in_sizes; (void)n_in; (void)out_size; (void)ws_size;
    const float* X  = (const float*)d_in[0];
    const float* Wq = (const float*)d_in[1];
    const float* Wk = (const float*)d_in[2];
    const float* Wv = (const float*)d_in[3];
    float* out = (float*)d_out;

    float* Qw = (float*)d_ws;                      // 64MB
    float* Kw = Qw + (size_t)MTOT * HDIM;          // 64MB
    float* Vw = Kw + (size_t)MTOT * HDIM;          // 64MB

    dim3 g1(HDIM / 128, MTOT / 128, 3);
    qkv_xpos_gemm<<<g1, 256, 0, stream>>>(X, Wq, Wk, Wv, Qw, Kw, Vw);

    retention_attn<<<dim3(BDIM * (LDIM / TQ)), 256, 0, stream>>>(Qw, Kw, Vw, out);
}

// Round 2
// 1172.051 us; speedup vs baseline: 2.8924x; 2.8924x over previous
//
#include <hip/hip_runtime.h>
#include <math.h>

// SimpleRetention bf16-MFMA pipeline.
// out = (softmax(QK^T) * gamma^|n-m|) @ V ; Q/K = xpos(X@W), V = X@Wv
// B=8 L=2048 H=Dh=1024.
//
// ws layout (161MB total; phase-aliased):
//   [0,64MB)    Wmat bf16 [8][2048][2048]   (phase2; aliases Xb+WT of phase1)
//   [0,32MB)    Xb  bf16 [16384][1024]      (phase1)
//   [32,38MB)   WT  bf16 [3][1024][1024]    (phase1, W transposed)
//   [64,96MB)   Qb  bf16 [16384][1024]
//   [96,128MB)  Kb  bf16 [16384][1024]
//   [128,160MB) Vt  bf16 [8][1024][2048]    (V transposed per batch)
//   [160,161MB) Zp  f32  [8][16][2048]      (softmax denom partials)

#define LDIM 2048
#define HDIM 1024
#define MTOT 16384

typedef unsigned short u16;
typedef __attribute__((ext_vector_type(4))) float f32x4;
typedef __attribute__((ext_vector_type(8))) short s16x8;

#define GLD16(gp, lp) __builtin_amdgcn_global_load_lds( \
    (const __attribute__((address_space(1))) void*)(gp), \
    (__attribute__((address_space(3))) void*)(lp), 16, 0, 0)

__device__ __forceinline__ u16 f2bf(float f) {
    unsigned u = __float_as_uint(f);
    return (u16)((u + 0x7FFFu + ((u >> 16) & 1u)) >> 16);
}

// ---------------------------------------------------------------------------
// Shared 128x128 bf16 MFMA GEMM core (m97 structure).
// C = A (row-major, [*,lda]) x B^T  with B row-major [*,ldb] (i.e. B^T layout).
// 256 thr = 4 waves (2x2), each wave 64x64 = 4x4 frags of 16x16x32 MFMA.
// smem: As[128][64] + Bs[128][64] bf16 = 32KB (front of the 34KB block buffer).
// ---------------------------------------------------------------------------
__device__ __forceinline__ void gemm128(const u16* __restrict__ A, const u16* __restrict__ B,
                                        int lda, int ldb, int K, int m0, int n0,
                                        char* smem, int tid, f32x4 (*acc)[4])
{
    u16* As = (u16*)smem;
    u16* Bs = As + 128 * 64;
    const int wv = tid >> 6, ln = tid & 63;
    const int wm = wv >> 1, wn = wv & 1;
    const int lr = ln & 15, lg = ln >> 4;
    const int srow = wv * 8 + (ln >> 3);   // staging row within 32-row group
    const int scol = (ln & 7) * 8;         // staging col (elements)

    for (int k0 = 0; k0 < K; k0 += 64) {
        __syncthreads();   // all waves done reading previous tile
#pragma unroll
        for (int i = 0; i < 4; ++i) {
            GLD16(A + (size_t)(m0 + i * 32 + srow) * lda + k0 + scol,
                  (char*)As + (i * 32 + wv * 8) * 128);
            GLD16(B + (size_t)(n0 + i * 32 + srow) * ldb + k0 + scol,
                  (char*)Bs + (i * 32 + wv * 8) * 128);
        }
        __syncthreads();   // drains vmcnt(0): tile resident
#pragma unroll
        for (int kk = 0; kk < 2; ++kk) {
            s16x8 af[4], bf[4];
#pragma unroll
            for (int f = 0; f < 4; ++f) {
                af[f] = *(const s16x8*)(As + (wm * 64 + f * 16 + lr) * 64 + kk * 32 + lg * 8);
                bf[f] = *(const s16x8*)(Bs + (wn * 64 + f * 16 + lr) * 64 + kk * 32 + lg * 8);
            }
#pragma unroll
            for (int i = 0; i < 4; ++i)
#pragma unroll
                for (int j = 0; j < 4; ++j)
                    acc[i][j] = __builtin_amdgcn_mfma_f32_16x16x32_bf16(af[i], bf[j], acc[i][j], 0, 0, 0);
        }
    }
    __syncthreads();   // safe to reuse smem in epilogue
}

// ---------------------------------------------------------------------------
// prep: X -> bf16
// ---------------------------------------------------------------------------
__global__ __launch_bounds__(256) void cast_x(const float* __restrict__ X,
                                              u16* __restrict__ Xb, int n4)
{
    int i = blockIdx.x * 256 + threadIdx.x;
    const int stride = gridDim.x * 256;
    for (; i < n4; i += stride) {
        float4 v = ((const float4*)X)[i];
        ushort4 o = make_ushort4(f2bf(v.x), f2bf(v.y), f2bf(v.z), f2bf(v.w));
        ((ushort4*)Xb)[i] = o;
    }
}

// ---------------------------------------------------------------------------
// prep: W (1024x1024 f32, [k][n]) -> WT bf16 [n][k], for z in {Q,K,V}
// ---------------------------------------------------------------------------
__global__ __launch_bounds__(256) void transw(const float* __restrict__ Wq,
                                              const float* __restrict__ Wk,
                                              const float* __restrict__ Wv,
                                              u16* __restrict__ WT)
{
    __shared__ float L[64][65];
    const int z = blockIdx.z;
    const float* Wz = (z == 0) ? Wq : (z == 1) ? Wk : Wv;
    u16* Oz = WT + (size_t)z * HDIM * HDIM;
    const int k0 = blockIdx.y * 64, n0 = blockIdx.x * 64;
    const int t = threadIdx.x;
    const int r_ = t >> 4, c4 = (t & 15) * 4;
#pragma unroll
    for (int it = 0; it < 4; ++it) {
        const int row = it * 16 + r_;
        float4 v = *(const float4*)&Wz[(size_t)(k0 + row) * HDIM + n0 + c4];
        L[row][c4 + 0] = v.x; L[row][c4 + 1] = v.y;
        L[row][c4 + 2] = v.z; L[row][c4 + 3] = v.w;
    }
    __syncthreads();
#pragma unroll
    for (int it = 0; it < 4; ++it) {
        const int orow = it * 16 + r_;   // n-local
        ushort4 o = make_ushort4(f2bf(L[c4 + 0][orow]), f2bf(L[c4 + 1][orow]),
                                 f2bf(L[c4 + 2][orow]), f2bf(L[c4 + 3][orow]));
        *(ushort4*)&Oz[(size_t)(n0 + orow) * HDIM + k0 + c4] = o;
    }
}

// ---------------------------------------------------------------------------
// K1: {Q,K,V} = X@W, xpos fused (fp32) for Q/K, V stored transposed.
// grid (8, 128, 3)
// ---------------------------------------------------------------------------
__global__ __launch_bounds__(256) void qkv_gemm(
    const u16* __restrict__ Xb, const u16* __restrict__ WT,
    u16* __restrict__ Qb, u16* __restrict__ Kb, u16* __restrict__ Vt)
{
    __shared__ __align__(16) char smem[128 * 136 * 2];
    const int z = blockIdx.z;
    const int m0 = blockIdx.y * 128, n0 = blockIdx.x * 128;
    const int tid = threadIdx.x;
    f32x4 zero4 = {0.f, 0.f, 0.f, 0.f};
    f32x4 acc[4][4];
#pragma unroll
    for (int i = 0; i < 4; ++i)
#pragma unroll
        for (int j = 0; j < 4; ++j) acc[i][j] = zero4;

    gemm128(Xb, WT + (size_t)z * HDIM * HDIM, HDIM, HDIM, HDIM, m0, n0, smem, tid, acc);

    const int wv = tid >> 6, ln = tid & 63;
    const int wm = wv >> 1, wn = wv & 1;
    const int lr = ln & 15, lg = ln >> 4;
    u16* T = (u16*)smem;   // [128][136]

    if (z < 2) {
        const float pwsgn = (z == 0) ? (1.f / 512.f) : (-1.f / 512.f);
#pragma unroll
        for (int fn = 0; fn < 4; ++fn) {
            const int gc = n0 + wn * 64 + fn * 16 + lr;
            const int ih = gc >> 1;
            const float invf = exp2f(-13.287712379549449f * (1.f / 512.f) * (float)ih);
            const float l2sv = log2f(((float)(2 * ih) + 409.6f) * (1.f / 1433.6f));
            const float sgn = (gc & 1) ? 1.f : -1.f;
#pragma unroll
            for (int fm = 0; fm < 4; ++fm) {
#pragma unroll
                for (int r = 0; r < 4; ++r) {
                    const int ml = wm * 64 + fm * 16 + lg * 4 + r;
                    const int lpos = (m0 + ml) & (LDIM - 1);
                    float c = acc[fm][fn][r];
                    float p = __shfl_xor(c, 1);   // even<->odd partner
                    float sn, cs;
                    sincosf((float)lpos * invf, &sn, &cs);
                    float scl = exp2f((float)lpos * pwsgn * l2sv);
                    T[ml * 136 + wn * 64 + fn * 16 + lr] = f2bf((c * cs + sgn * p * sn) * scl);
                }
            }
        }
    } else {
        // V: repack transposed  T[n_local][m_local]
#pragma unroll
        for (int fn = 0; fn < 4; ++fn)
#pragma unroll
            for (int fm = 0; fm < 4; ++fm)
#pragma unroll
                for (int r = 0; r < 4; ++r)
                    T[(wn * 64 + fn * 16 + lr) * 136 + wm * 64 + fm * 16 + lg * 4 + r] =
                        f2bf(acc[fm][fn][r]);
    }
    __syncthreads();

    const int row_ = tid >> 4, colb = (tid & 15) * 8;
    if (z < 2) {
        u16* Out = (z == 0) ? Qb : Kb;
#pragma unroll
        for (int g = 0; g < 8; ++g) {
            const int row = g * 16 + row_;
            s16x8 v = *(const s16x8*)&T[row * 136 + colb];
            *(s16x8*)&Out[(size_t)(m0 + row) * HDIM + n0 + colb] = v;
        }
    } else {
        const int b = m0 >> 11, l0 = m0 & (LDIM - 1);
#pragma unroll
        for (int g = 0; g < 8; ++g) {
            const int row = g * 16 + row_;   // n-local (d index)
            s16x8 v = *(const s16x8*)&T[row * 136 + colb];
            *(s16x8*)&Vt[((size_t)b * HDIM + n0 + row) * LDIM + l0 + colb] = v;
        }
    }
}

// ---------------------------------------------------------------------------
// K2a: W = exp(s)*gamma^|q-k| (bf16) + Z partials (fp32, deterministic).
// grid 2048: b = bid&7 (XCD-pinned), mt/nt = 16x16 tiles of 128.
// ---------------------------------------------------------------------------
__global__ __launch_bounds__(256) void qk_gemm(
    const u16* __restrict__ Q, const u16* __restrict__ Km,
    u16* __restrict__ Wm, float* __restrict__ Zp)
{
    __shared__ __align__(16) char smem[128 * 136 * 2];
    __shared__ float Zl[2][128];
    const int bid = blockIdx.x;
    const int b = bid & 7, tt = bid >> 3, mt = tt & 15, nt = tt >> 4;
    const int m0 = mt * 128, n0 = nt * 128;
    const int tid = threadIdx.x;
    f32x4 zero4 = {0.f, 0.f, 0.f, 0.f};
    f32x4 acc[4][4];
#pragma unroll
    for (int i = 0; i < 4; ++i)
#pragma unroll
        for (int j = 0; j < 4; ++j) acc[i][j] = zero4;

    gemm128(Q + (size_t)b * LDIM * HDIM, Km + (size_t)b * LDIM * HDIM,
            HDIM, HDIM, HDIM, m0, n0, smem, tid, acc);

    const int wv = tid >> 6, ln = tid & 63;
    const int wm = wv >> 1, wn = wv & 1;
    const int lr = ln & 15, lg = ln >> 4;
    u16* T = (u16*)smem;   // [128][136]
    const float LOG2E = 1.4426950408889634f;
    const float LOG2G = -0.15200309344504997f;   // log2(0.9)

    float psum[4][4];
#pragma unroll
    for (int i = 0; i < 4; ++i)
#pragma unroll
        for (int r = 0; r < 4; ++r) psum[i][r] = 0.f;

#pragma unroll
    for (int fm = 0; fm < 4; ++fm) {
#pragma unroll
        for (int fn = 0; fn < 4; ++fn) {
            const int gk = n0 + wn * 64 + fn * 16 + lr;
#pragma unroll
            for (int r = 0; r < 4; ++r) {
                const int gq = m0 + wm * 64 + fm * 16 + lg * 4 + r;
                float t1 = acc[fm][fn][r] * LOG2E;
                float e = exp2f(t1);
                int dd = gq - gk; dd = dd < 0 ? -dd : dd;
                psum[fm][r] += e;
                T[(wm * 64 + fm * 16 + lg * 4 + r) * 136 + wn * 64 + fn * 16 + lr] =
                    f2bf(exp2f(t1 + (float)dd * LOG2G));
            }
        }
    }
    // reduce e-sums across the 16 col-lanes of each group
#pragma unroll
    for (int fm = 0; fm < 4; ++fm)
#pragma unroll
        for (int r = 0; r < 4; ++r) {
            float s = psum[fm][r];
            s += __shfl_xor(s, 1); s += __shfl_xor(s, 2);
            s += __shfl_xor(s, 4); s += __shfl_xor(s, 8);
            if (lr == 0) Zl[wn][wm * 64 + fm * 16 + lg * 4 + r] = s;
        }
    __syncthreads();

    const int row_ = tid >> 4, colb = (tid & 15) * 8;
#pragma unroll
    for (int g = 0; g < 8; ++g) {
        const int row = g * 16 + row_;
        s16x8 v = *(const s16x8*)&T[row * 136 + colb];
        *(s16x8*)&Wm[((size_t)b * LDIM + m0 + row) * LDIM + n0 + colb] = v;
    }
    if (tid < 128)
        Zp[((size_t)b * 16 + nt) * LDIM + m0 + tid] = Zl[0][tid] + Zl[1][tid];
}

// ---------------------------------------------------------------------------
// K2b: O = (W @ V) / Z  (fp32 out).  grid 1024: b=bid&7, 16 mt x 8 nt.
// ---------------------------------------------------------------------------
__global__ __launch_bounds__(256) void pv_gemm(
    const u16* __restrict__ Wm, const u16* __restrict__ Vt,
    const float* __restrict__ Zp, float* __restrict__ Out)
{
    __shared__ __align__(16) char smem[128 * 136 * 2];
    __shared__ float Zinv[128];
    const int bid = blockIdx.x;
    const int b = bid & 7, tt = bid >> 3, mt = tt & 15, nt = tt >> 4;
    const int m0 = mt * 128, n0 = nt * 128;
    const int tid = threadIdx.x;

    if (tid < 128) {
        float zz = 0.f;
#pragma unroll
        for (int nb = 0; nb < 16; ++nb)
            zz += Zp[((size_t)b * 16 + nb) * LDIM + m0 + tid];
        Zinv[tid] = 1.0f / zz;
    }

    f32x4 zero4 = {0.f, 0.f, 0.f, 0.f};
    f32x4 acc[4][4];
#pragma unroll
    for (int i = 0; i < 4; ++i)
#pragma unroll
        for (int j = 0; j < 4; ++j) acc[i][j] = zero4;

    gemm128(Wm + (size_t)b * LDIM * LDIM, Vt + (size_t)b * HDIM * LDIM,
            LDIM, LDIM, LDIM, m0, n0, smem, tid, acc);

    const int wv = tid >> 6, ln = tid & 63;
    const int wm = wv >> 1, wn = wv & 1;
    const int lr = ln & 15, lg = ln >> 4;
    float* Ob = Out + (size_t)b * LDIM * HDIM;
#pragma unroll
    for (int fm = 0; fm < 4; ++fm)
#pragma unroll
        for (int fn = 0; fn < 4; ++fn) {
            const int gn = n0 + wn * 64 + fn * 16 + lr;
#pragma unroll
            for (int r = 0; r < 4; ++r) {
                const int row = wm * 64 + fm * 16 + lg * 4 + r;
                Ob[(size_t)(m0 + row) * HDIM + gn] = acc[fm][fn][r] * Zinv[row];
            }
        }
}

// ---------------------------------------------------------------------------
extern "C" void kernel_launch(void* const* d_in, const int* in_sizes, int n_in,
                              void* d_out, int out_size, void* d_ws, size_t ws_size,
                              hipStream_t stream)
{
    (void)in_sizes; (void)n_in; (void)out_size; (void)ws_size;
    const float* X  = (const float*)d_in[0];
    const float* Wq = (const float*)d_in[1];
    const float* Wk = (const float*)d_in[2];
    const float* Wv = (const float*)d_in[3];
    char* ws = (char*)d_ws;
    const size_t MB = 1024 * 1024;

    u16* Wmat = (u16*)ws;                 // phase2, aliases Xb+WT
    u16* Xb   = (u16*)ws;                 // phase1
    u16* WT   = (u16*)(ws + 32 * MB);     // phase1
    u16* Qb   = (u16*)(ws + 64 * MB);
    u16* Kb   = (u16*)(ws + 96 * MB);
    u16* Vt   = (u16*)(ws + 128 * MB);
    float* Zp = (float*)(ws + 160 * MB);

    cast_x<<<2048, 256, 0, stream>>>(X, Xb, MTOT * HDIM / 4);
    transw<<<dim3(16, 16, 3), 256, 0, stream>>>(Wq, Wk, Wv, WT);
    qkv_gemm<<<dim3(8, 128, 3), 256, 0, stream>>>(Xb, WT, Qb, Kb, Vt);
    qk_gemm<<<2048, 256, 0, stream>>>(Qb, Kb, Wmat, Zp);
    pv_gemm<<<1024, 256, 0, stream>>>(Wmat, Vt, Zp, (float*)d_out);
}

// Round 3
// 409.012 us; speedup vs baseline: 8.2885x; 2.8656x over previous
//
#include <hip/hip_runtime.h>
#include <math.h>

// SimpleRetention bf16-MFMA pipeline, round 3.
// out = (softmax(QK^T) * gamma^|n-m|) @ V ; Q/K = xpos(X@W), V = X@Wv
// B=8 L=2048 H=Dh=1024.
//
// Round-3 changes vs round-2:
//  - XCD-chunked block decode in all three GEMMs (A/Q/W panels L2-resident
//    per XCD; kills qkv's 786MB X re-fetch + associated write anomaly).
//  - sincosf -> exact f64 revolution reduction + v_sin_f32/v_cos_f32.
//
// ws layout (161MB total; phase-aliased):
//   [0,64MB)    Wmat bf16 [8][2048][2048]   (phase2; aliases Xb+WT of phase1)
//   [0,32MB)    Xb  bf16 [16384][1024]      (phase1)
//   [32,38MB)   WT  bf16 [3][1024][1024]    (phase1, W transposed)
//   [64,96MB)   Qb  bf16 [16384][1024]
//   [96,128MB)  Kb  bf16 [16384][1024]
//   [128,160MB) Vt  bf16 [8][1024][2048]    (V transposed per batch)
//   [160,161MB) Zp  f32  [8][16][2048]      (softmax denom partials)

#define LDIM 2048
#define HDIM 1024
#define MTOT 16384

typedef unsigned short u16;
typedef __attribute__((ext_vector_type(4))) float f32x4;
typedef __attribute__((ext_vector_type(8))) short s16x8;

#define GLD16(gp, lp) __builtin_amdgcn_global_load_lds( \
    (const __attribute__((address_space(1))) void*)(gp), \
    (__attribute__((address_space(3))) void*)(lp), 16, 0, 0)

__device__ __forceinline__ u16 f2bf(float f) {
    unsigned u = __float_as_uint(f);
    return (u16)((u + 0x7FFFu + ((u >> 16) & 1u)) >> 16);
}

// sin/cos(ang) via exact-enough reduction: rev = ang/(2pi) in f64, fract,
// then HW v_sin/v_cos (input in revolutions). Error ~1e-6 rad << bf16 noise.
__device__ __forceinline__ void sincos_rev(float ang, float* sn, float* cs) {
    double dr = (double)ang * 0.15915494309189535;   // 1/(2*pi)
    dr -= __builtin_floor(dr);
    float fr = (float)dr;
    float s_, c_;
    asm("v_sin_f32 %0, %1" : "=v"(s_) : "v"(fr));
    asm("v_cos_f32 %0, %1" : "=v"(c_) : "v"(fr));
    *sn = s_; *cs = c_;
}

// ---------------------------------------------------------------------------
// Shared 128x128 bf16 MFMA GEMM core (m97 structure).
// C = A (row-major, [*,lda]) x B^T  with B row-major [*,ldb].
// 256 thr = 4 waves (2x2), each wave 64x64 = 4x4 frags of 16x16x32 MFMA.
// ---------------------------------------------------------------------------
__device__ __forceinline__ void gemm128(const u16* __restrict__ A, const u16* __restrict__ B,
                                        int lda, int ldb, int K, int m0, int n0,
                                        char* smem, int tid, f32x4 (*acc)[4])
{
    u16* As = (u16*)smem;
    u16* Bs = As + 128 * 64;
    const int wv = tid >> 6, ln = tid & 63;
    const int wm = wv >> 1, wn = wv & 1;
    const int lr = ln & 15, lg = ln >> 4;
    const int srow = wv * 8 + (ln >> 3);   // staging row within 32-row group
    const int scol = (ln & 7) * 8;         // staging col (elements)

    for (int k0 = 0; k0 < K; k0 += 64) {
        __syncthreads();   // all waves done reading previous tile
#pragma unroll
        for (int i = 0; i < 4; ++i) {
            GLD16(A + (size_t)(m0 + i * 32 + srow) * lda + k0 + scol,
                  (char*)As + (i * 32 + wv * 8) * 128);
            GLD16(B + (size_t)(n0 + i * 32 + srow) * ldb + k0 + scol,
                  (char*)Bs + (i * 32 + wv * 8) * 128);
        }
        __syncthreads();   // drains vmcnt(0): tile resident
#pragma unroll
        for (int kk = 0; kk < 2; ++kk) {
            s16x8 af[4], bf[4];
#pragma unroll
            for (int f = 0; f < 4; ++f) {
                af[f] = *(const s16x8*)(As + (wm * 64 + f * 16 + lr) * 64 + kk * 32 + lg * 8);
                bf[f] = *(const s16x8*)(Bs + (wn * 64 + f * 16 + lr) * 64 + kk * 32 + lg * 8);
            }
#pragma unroll
            for (int i = 0; i < 4; ++i)
#pragma unroll
                for (int j = 0; j < 4; ++j)
                    acc[i][j] = __builtin_amdgcn_mfma_f32_16x16x32_bf16(af[i], bf[j], acc[i][j], 0, 0, 0);
        }
    }
    __syncthreads();   // safe to reuse smem in epilogue
}

// ---------------------------------------------------------------------------
// prep: X -> bf16
// ---------------------------------------------------------------------------
__global__ __launch_bounds__(256) void cast_x(const float* __restrict__ X,
                                              u16* __restrict__ Xb, int n4)
{
    int i = blockIdx.x * 256 + threadIdx.x;
    const int stride = gridDim.x * 256;
    for (; i < n4; i += stride) {
        float4 v = ((const float4*)X)[i];
        ushort4 o = make_ushort4(f2bf(v.x), f2bf(v.y), f2bf(v.z), f2bf(v.w));
        ((ushort4*)Xb)[i] = o;
    }
}

// ---------------------------------------------------------------------------
// prep: W (1024x1024 f32, [k][n]) -> WT bf16 [n][k], for z in {Q,K,V}
// ---------------------------------------------------------------------------
__global__ __launch_bounds__(256) void transw(const float* __restrict__ Wq,
                                              const float* __restrict__ Wk,
                                              const float* __restrict__ Wv,
                                              u16* __restrict__ WT)
{
    __shared__ float L[64][65];
    const int z = blockIdx.z;
    const float* Wz = (z == 0) ? Wq : (z == 1) ? Wk : Wv;
    u16* Oz = WT + (size_t)z * HDIM * HDIM;
    const int k0 = blockIdx.y * 64, n0 = blockIdx.x * 64;
    const int t = threadIdx.x;
    const int r_ = t >> 4, c4 = (t & 15) * 4;
#pragma unroll
    for (int it = 0; it < 4; ++it) {
        const int row = it * 16 + r_;
        float4 v = *(const float4*)&Wz[(size_t)(k0 + row) * HDIM + n0 + c4];
        L[row][c4 + 0] = v.x; L[row][c4 + 1] = v.y;
        L[row][c4 + 2] = v.z; L[row][c4 + 3] = v.w;
    }
    __syncthreads();
#pragma unroll
    for (int it = 0; it < 4; ++it) {
        const int orow = it * 16 + r_;   // n-local
        ushort4 o = make_ushort4(f2bf(L[c4 + 0][orow]), f2bf(L[c4 + 1][orow]),
                                 f2bf(L[c4 + 2][orow]), f2bf(L[c4 + 3][orow]));
        *(ushort4*)&Oz[(size_t)(n0 + orow) * HDIM + k0 + c4] = o;
    }
}

// ---------------------------------------------------------------------------
// K1: {Q,K,V} = X@W, xpos fused (fp32) for Q/K, V stored transposed.
// 1D grid 3072, XCD-chunked: each XCD owns 16 contiguous m-tiles (2MB A-chunks
// hot in its L2 across the n x z sweep). decode: xcd(8) | mh(2) n(8) z(3) m8(8)
// ---------------------------------------------------------------------------
__global__ __launch_bounds__(256) void qkv_gemm(
    const u16* __restrict__ Xb, const u16* __restrict__ WT,
    u16* __restrict__ Qb, u16* __restrict__ Kb, u16* __restrict__ Vt)
{
    __shared__ __align__(16) char smem[128 * 136 * 2];
    const int bid = blockIdx.x;
    const int xcd = bid & 7, t = bid >> 3;   // t in [0,384)
    const int m8 = t & 7;
    const int u_ = t >> 3;                   // [0,48)
    const int z  = u_ % 3;
    const int v_ = u_ / 3;                   // [0,16)
    const int n_ = v_ & 7;
    const int mh = v_ >> 3;
    const int m0 = (xcd * 16 + mh * 8 + m8) * 128;
    const int n0 = n_ * 128;
    const int tid = threadIdx.x;

    f32x4 zero4 = {0.f, 0.f, 0.f, 0.f};
    f32x4 acc[4][4];
#pragma unroll
    for (int i = 0; i < 4; ++i)
#pragma unroll
        for (int j = 0; j < 4; ++j) acc[i][j] = zero4;

    gemm128(Xb, WT + (size_t)z * HDIM * HDIM, HDIM, HDIM, HDIM, m0, n0, smem, tid, acc);

    const int wv = tid >> 6, ln = tid & 63;
    const int wm = wv >> 1, wn = wv & 1;
    const int lr = ln & 15, lg = ln >> 4;
    u16* T = (u16*)smem;   // [128][136]

    if (z < 2) {
        const float pwsgn = (z == 0) ? (1.f / 512.f) : (-1.f / 512.f);
#pragma unroll
        for (int fn = 0; fn < 4; ++fn) {
            const int gc = n0 + wn * 64 + fn * 16 + lr;
            const int ih = gc >> 1;
            const float invf = exp2f(-13.287712379549449f * (1.f / 512.f) * (float)ih);
            const float l2sv = log2f(((float)(2 * ih) + 409.6f) * (1.f / 1433.6f));
            const float sgn = (gc & 1) ? 1.f : -1.f;
#pragma unroll
            for (int fm = 0; fm < 4; ++fm) {
#pragma unroll
                for (int r = 0; r < 4; ++r) {
                    const int ml = wm * 64 + fm * 16 + lg * 4 + r;
                    const int lpos = (m0 + ml) & (LDIM - 1);
                    float c = acc[fm][fn][r];
                    float p = __shfl_xor(c, 1);   // even<->odd partner
                    float sn, cs;
                    sincos_rev((float)lpos * invf, &sn, &cs);
                    float scl = exp2f((float)lpos * pwsgn * l2sv);
                    T[ml * 136 + wn * 64 + fn * 16 + lr] = f2bf((c * cs + sgn * p * sn) * scl);
                }
            }
        }
    } else {
        // V: repack transposed  T[n_local][m_local]
#pragma unroll
        for (int fn = 0; fn < 4; ++fn)
#pragma unroll
            for (int fm = 0; fm < 4; ++fm)
#pragma unroll
                for (int r = 0; r < 4; ++r)
                    T[(wn * 64 + fn * 16 + lr) * 136 + wm * 64 + fm * 16 + lg * 4 + r] =
                        f2bf(acc[fm][fn][r]);
    }
    __syncthreads();

    const int row_ = tid >> 4, colb = (tid & 15) * 8;
    if (z < 2) {
        u16* Out = (z == 0) ? Qb : Kb;
#pragma unroll
        for (int g = 0; g < 8; ++g) {
            const int row = g * 16 + row_;
            s16x8 v = *(const s16x8*)&T[row * 136 + colb];
            *(s16x8*)&Out[(size_t)(m0 + row) * HDIM + n0 + colb] = v;
        }
    } else {
        const int b = m0 >> 11, l0 = m0 & (LDIM - 1);
#pragma unroll
        for (int g = 0; g < 8; ++g) {
            const int row = g * 16 + row_;   // n-local (d index)
            s16x8 v = *(const s16x8*)&T[row * 136 + colb];
            *(s16x8*)&Vt[((size_t)b * HDIM + n0 + row) * LDIM + l0 + colb] = v;
        }
    }
}

// ---------------------------------------------------------------------------
// K2a: W = exp(s)*gamma^|q-k| (bf16) + Z partials (fp32, deterministic).
// grid 2048: b = bid&7 (XCD-pinned). decode: mtH(2) nt(16) mt8(8) --
// 2MB Q-chunk hot across the full nt sweep.
// ---------------------------------------------------------------------------
__global__ __launch_bounds__(256) void qk_gemm(
    const u16* __restrict__ Q, const u16* __restrict__ Km,
    u16* __restrict__ Wm, float* __restrict__ Zp)
{
    __shared__ __align__(16) char smem[128 * 136 * 2];
    __shared__ float Zl[2][128];
    const int bid = blockIdx.x;
    const int b = bid & 7, t = bid >> 3;     // t in [0,256)
    const int mt8 = t & 7;
    const int w_ = t >> 3;                   // [0,32)
    const int nt = w_ & 15;
    const int mtH = w_ >> 4;
    const int m0 = (mtH * 8 + mt8) * 128;
    const int n0 = nt * 128;
    const int tid = threadIdx.x;
    f32x4 zero4 = {0.f, 0.f, 0.f, 0.f};
    f32x4 acc[4][4];
#pragma unroll
    for (int i = 0; i < 4; ++i)
#pragma unroll
        for (int j = 0; j < 4; ++j) acc[i][j] = zero4;

    gemm128(Q + (size_t)b * LDIM * HDIM, Km + (size_t)b * LDIM * HDIM,
            HDIM, HDIM, HDIM, m0, n0, smem, tid, acc);

    const int wv = tid >> 6, ln = tid & 63;
    const int wm = wv >> 1, wn = wv & 1;
    const int lr = ln & 15, lg = ln >> 4;
    u16* T = (u16*)smem;   // [128][136]
    const float LOG2E = 1.4426950408889634f;
    const float LOG2G = -0.15200309344504997f;   // log2(0.9)

    float psum[4][4];
#pragma unroll
    for (int i = 0; i < 4; ++i)
#pragma unroll
        for (int r = 0; r < 4; ++r) psum[i][r] = 0.f;

#pragma unroll
    for (int fm = 0; fm < 4; ++fm) {
#pragma unroll
        for (int fn = 0; fn < 4; ++fn) {
            const int gk = n0 + wn * 64 + fn * 16 + lr;
#pragma unroll
            for (int r = 0; r < 4; ++r) {
                const int gq = m0 + wm * 64 + fm * 16 + lg * 4 + r;
                float t1 = acc[fm][fn][r] * LOG2E;
                float e = exp2f(t1);
                int dd = gq - gk; dd = dd < 0 ? -dd : dd;
                psum[fm][r] += e;
                T[(wm * 64 + fm * 16 + lg * 4 + r) * 136 + wn * 64 + fn * 16 + lr] =
                    f2bf(exp2f(t1 + (float)dd * LOG2G));
            }
        }
    }
    // reduce e-sums across the 16 col-lanes of each group
#pragma unroll
    for (int fm = 0; fm < 4; ++fm)
#pragma unroll
        for (int r = 0; r < 4; ++r) {
            float s = psum[fm][r];
            s += __shfl_xor(s, 1); s += __shfl_xor(s, 2);
            s += __shfl_xor(s, 4); s += __shfl_xor(s, 8);
            if (lr == 0) Zl[wn][wm * 64 + fm * 16 + lg * 4 + r] = s;
        }
    __syncthreads();

    const int row_ = tid >> 4, colb = (tid & 15) * 8;
#pragma unroll
    for (int g = 0; g < 8; ++g) {
        const int row = g * 16 + row_;
        s16x8 v = *(const s16x8*)&T[row * 136 + colb];
        *(s16x8*)&Wm[((size_t)b * LDIM + m0 + row) * LDIM + n0 + colb] = v;
    }
    if (tid < 128)
        Zp[((size_t)b * 16 + nt) * LDIM + m0 + tid] = Zl[0][tid] + Zl[1][tid];
}

// ---------------------------------------------------------------------------
// K2b: O = (W @ V) / Z  (fp32 out).  grid 1024: b=bid&7.
// decode: mtQ(4) nt(8) mt4(4) -- 2MB W-chunk hot across the nt sweep.
// ---------------------------------------------------------------------------
__global__ __launch_bounds__(256) void pv_gemm(
    const u16* __restrict__ Wm, const u16* __restrict__ Vt,
    const float* __restrict__ Zp, float* __restrict__ Out)
{
    __shared__ __align__(16) char smem[128 * 136 * 2];
    __shared__ float Zinv[128];
    const int bid = blockIdx.x;
    const int b = bid & 7, t = bid >> 3;     // t in [0,128)
    const int mt4 = t & 3;
    const int w_ = t >> 2;                   // [0,32)
    const int nt = w_ & 7;
    const int mtQ = w_ >> 3;
    const int m0 = (mtQ * 4 + mt4) * 128;
    const int n0 = nt * 128;
    const int tid = threadIdx.x;

    if (tid < 128) {
        float zz = 0.f;
#pragma unroll
        for (int nb = 0; nb < 16; ++nb)
            zz += Zp[((size_t)b * 16 + nb) * LDIM + m0 + tid];
        Zinv[tid] = 1.0f / zz;
    }

    f32x4 zero4 = {0.f, 0.f, 0.f, 0.f};
    f32x4 acc[4][4];
#pragma unroll
    for (int i = 0; i < 4; ++i)
#pragma unroll
        for (int j = 0; j < 4; ++j) acc[i][j] = zero4;

    gemm128(Wm + (size_t)b * LDIM * LDIM, Vt + (size_t)b * HDIM * LDIM,
            LDIM, LDIM, LDIM, m0, n0, smem, tid, acc);

    const int wv = tid >> 6, ln = tid & 63;
    const int wm = wv >> 1, wn = wv & 1;
    const int lr = ln & 15, lg = ln >> 4;
    float* Ob = Out + (size_t)b * LDIM * HDIM;
#pragma unroll
    for (int fm = 0; fm < 4; ++fm)
#pragma unroll
        for (int fn = 0; fn < 4; ++fn) {
            const int gn = n0 + wn * 64 + fn * 16 + lr;
#pragma unroll
            for (int r = 0; r < 4; ++r) {
                const int row = wm * 64 + fm * 16 + lg * 4 + r;
                Ob[(size_t)(m0 + row) * HDIM + gn] = acc[fm][fn][r] * Zinv[row];
            }
        }
}

// ---------------------------------------------------------------------------
extern "C" void kernel_launch(void* const* d_in, const int* in_sizes, int n_in,
                              void* d_out, int out_size, void* d_ws, size_t ws_size,
                              hipStream_t stream)
{
    (void)in_sizes; (void)n_in; (void)out_size; (void)ws_size;
    const float* X  = (const float*)d_in[0];
    const float* Wq = (const float*)d_in[1];
    const float* Wk = (const float*)d_in[2];
    const float* Wv = (const float*)d_in[3];
    char* ws = (char*)d_ws;
    const size_t MB = 1024 * 1024;

    u16* Wmat = (u16*)ws;                 // phase2, aliases Xb+WT
    u16* Xb   = (u16*)ws;                 // phase1
    u16* WT   = (u16*)(ws + 32 * MB);     // phase1
    u16* Qb   = (u16*)(ws + 64 * MB);
    u16* Kb   = (u16*)(ws + 96 * MB);
    u16* Vt   = (u16*)(ws + 128 * MB);
    float* Zp = (float*)(ws + 160 * MB);

    cast_x<<<2048, 256, 0, stream>>>(X, Xb, MTOT * HDIM / 4);
    transw<<<dim3(16, 16, 3), 256, 0, stream>>>(Wq, Wk, Wv, WT);
    qkv_gemm<<<3072, 256, 0, stream>>>(Xb, WT, Qb, Kb, Vt);
    qk_gemm<<<2048, 256, 0, stream>>>(Qb, Kb, Wmat, Zp);
    pv_gemm<<<1024, 256, 0, stream>>>(Wmat, Vt, Zp, (float*)d_out);
}